// Round 1
// baseline (2420.541 us; speedup 1.0000x reference)
//
#include <hip/hip_runtime.h>
#include <math.h>

// Problem constants
#define B_    8
#define E_    512
#define L_    8192
#define K_    5
#define LC    8188      // L - K + 1 (valid conv output length)
#define LOUT  4096      // L / DS

// Conv tiling: block tile 64e x 256t, per-thread 4e x (4 subtiles x 4t)
#define EE    64
#define TT    256
#define NSUB  4
#define IC    16

// ---------------------------------------------------------------------------
// Kernel 0: transpose conv weight [e][i][k] -> Wt[(i*K+k)*E + e] so the conv
// kernel's LDS staging loads are coalesced in e.
// ---------------------------------------------------------------------------
__global__ __launch_bounds__(256) void wt_kernel(const float* __restrict__ w,
                                                 float* __restrict__ Wt) {
    int idx = blockIdx.x * 256 + threadIdx.x;
    if (idx >= E_ * E_ * K_) return;
    int e    = idx & (E_ - 1);
    int rest = idx >> 9;            // i*K + k
    int k    = rest % K_;
    int i    = rest / K_;
    Wt[idx] = w[((size_t)e * E_ + i) * K_ + k];
}

// ---------------------------------------------------------------------------
// Kernel 1: valid conv1d + bias. y[b,e,t] = bias[e] + sum_{i,k} W[e,i,k]*x[b,i,t+k]
// ---------------------------------------------------------------------------
__global__ __launch_bounds__(256) void conv_kernel(const float* __restrict__ x,
                                                   const float* __restrict__ Wt,
                                                   const float* __restrict__ bias,
                                                   float* __restrict__ y) {
    __shared__ float xs[IC][TT + 4];    // [16][260] = 16.6 KB, rows 16B-aligned
    __shared__ float wsh[IC][K_][EE];   // [16][5][64] = 20.5 KB

    const int b   = blockIdx.z;
    const int e0  = blockIdx.y * EE;
    const int t0  = blockIdx.x * TT;
    const int tid = threadIdx.x;
    const int tx  = tid & 15;           // t-group (16 groups of 4t, x4 subtiles)
    const int ty  = tid >> 4;           // e-group (16 groups of 4e)

    float acc[NSUB][4][4];
    #pragma unroll
    for (int s = 0; s < NSUB; ++s)
        #pragma unroll
        for (int a = 0; a < 4; ++a)
            #pragma unroll
            for (int c = 0; c < 4; ++c) acc[s][a][c] = 0.f;

    const float* xb = x + (size_t)b * E_ * L_;

    for (int i0 = 0; i0 < E_; i0 += IC) {
        // stage x tile: xs[r][c] = x[b, i0+r, t0+c] (0 past end)
        for (int idx = tid; idx < IC * (TT + 4); idx += 256) {
            int r = idx / (TT + 4);
            int c = idx - r * (TT + 4);
            int t = t0 + c;
            xs[r][c] = (t < L_) ? xb[(size_t)(i0 + r) * L_ + t] : 0.f;
        }
        // stage W tile: wsh[ii][k][e'] = Wt[((i0+ii)*K+k)*E + e0+e']  (coalesced)
        for (int idx = tid; idx < IC * K_ * EE; idx += 256) {
            int rest = idx >> 6;        // ii*K + k  (0..79)
            ((float*)wsh)[idx] = Wt[(size_t)(i0 * K_ + rest) * E_ + e0 + (idx & 63)];
        }
        __syncthreads();

        #pragma unroll 4
        for (int ii = 0; ii < IC; ++ii) {
            float wv[K_][4];
            #pragma unroll
            for (int k = 0; k < K_; ++k) {
                const float4 w4 = *(const float4*)&wsh[ii][k][ty * 4];
                wv[k][0] = w4.x; wv[k][1] = w4.y; wv[k][2] = w4.z; wv[k][3] = w4.w;
            }
            #pragma unroll
            for (int sub = 0; sub < NSUB; ++sub) {
                float xv[8];
                const float4 x0 = *(const float4*)&xs[ii][sub * 64 + tx * 4];
                const float4 x1 = *(const float4*)&xs[ii][sub * 64 + tx * 4 + 4];
                xv[0] = x0.x; xv[1] = x0.y; xv[2] = x0.z; xv[3] = x0.w;
                xv[4] = x1.x; xv[5] = x1.y; xv[6] = x1.z; xv[7] = x1.w;
                #pragma unroll
                for (int k = 0; k < K_; ++k)
                    #pragma unroll
                    for (int ee = 0; ee < 4; ++ee)
                        #pragma unroll
                        for (int tt = 0; tt < 4; ++tt)
                            acc[sub][ee][tt] = fmaf(wv[k][ee], xv[tt + k], acc[sub][ee][tt]);
            }
        }
        __syncthreads();
    }

    // epilogue: add bias, store y
    #pragma unroll
    for (int ee = 0; ee < 4; ++ee) {
        int e = e0 + ty * 4 + ee;
        float bv = bias[e];
        float* yrow = y + ((size_t)b * E_ + e) * LC;
        #pragma unroll
        for (int sub = 0; sub < NSUB; ++sub) {
            int tbase = t0 + sub * 64 + tx * 4;
            #pragma unroll
            for (int tt = 0; tt < 4; ++tt) {
                int t = tbase + tt;
                if (t < LC) yrow[t] = acc[sub][ee][tt] + bv;
            }
        }
    }
}

// ---------------------------------------------------------------------------
// Kernel 2: z[b,t] = sum_e y[b,e,t] * score_w[e]
// ---------------------------------------------------------------------------
__global__ __launch_bounds__(256) void zscore_kernel(const float* __restrict__ y,
                                                     const float* __restrict__ sw,
                                                     float* __restrict__ z) {
    __shared__ float s[E_];
    const int b = blockIdx.y;
    const int t = blockIdx.x * 256 + threadIdx.x;
    for (int i = threadIdx.x; i < E_; i += 256) s[i] = sw[i];
    __syncthreads();
    if (t >= LC) return;
    const float* yb = y + (size_t)b * E_ * LC + t;
    float a0 = 0, a1 = 0, a2 = 0, a3 = 0, a4 = 0, a5 = 0, a6 = 0, a7 = 0;
    #pragma unroll 2
    for (int e = 0; e < E_; e += 8) {
        a0 += yb[(size_t)(e + 0) * LC] * s[e + 0];
        a1 += yb[(size_t)(e + 1) * LC] * s[e + 1];
        a2 += yb[(size_t)(e + 2) * LC] * s[e + 2];
        a3 += yb[(size_t)(e + 3) * LC] * s[e + 3];
        a4 += yb[(size_t)(e + 4) * LC] * s[e + 4];
        a5 += yb[(size_t)(e + 5) * LC] * s[e + 5];
        a6 += yb[(size_t)(e + 6) * LC] * s[e + 6];
        a7 += yb[(size_t)(e + 7) * LC] * s[e + 7];
    }
    z[(size_t)b * LC + t] = ((a0 + a1) + (a2 + a3)) + ((a4 + a5) + (a6 + a7));
}

// ---------------------------------------------------------------------------
// Kernel 3: per (b,e): candidate means (w=1,2,3) from y, softmax over widths
// using z-derived scores, blend, then 2x avg-pool downsample.
// All GBST pad/truncate semantics follow from zero-extending y and z past LC.
// ---------------------------------------------------------------------------
#define DTILE 256
#define STAGE 520
__global__ __launch_bounds__(256) void out_kernel(const float* __restrict__ y,
                                                  const float* __restrict__ z,
                                                  float* __restrict__ out) {
    __shared__ float ys[STAGE];
    __shared__ float zs[STAGE];
    const int be = blockIdx.x;          // b*E + e
    const int b  = be >> 9;
    const int d0 = blockIdx.y * DTILE;
    const int tb = d0 * 2;              // time base; ys[i] = y[tb-2+i]
    const float* yrow = y + (size_t)be * LC;
    const float* zrow = z + (size_t)b * LC;
    for (int i = threadIdx.x; i < STAGE; i += 256) {
        int t = tb - 2 + i;
        bool v = (t >= 0) && (t < LC);
        ys[i] = v ? yrow[t] : 0.f;
        zs[i] = v ? zrow[t] : 0.f;
    }
    __syncthreads();
    const int d = d0 + threadIdx.x;
    float o = 0.f;
    #pragma unroll
    for (int half = 0; half < 2; ++half) {
        int t = 2 * d + half;
        int j = t - tb + 2;
        float C1 = ys[j], S1 = zs[j];
        int i2 = (t & ~1) - tb + 2;
        float C2 = 0.5f * (ys[i2] + ys[i2 + 1]);
        float S2 = 0.5f * (zs[i2] + zs[i2 + 1]);
        int i3 = (t / 3) * 3 - tb + 2;
        float C3 = (ys[i3] + ys[i3 + 1] + ys[i3 + 2]) * (1.f / 3.f);
        float S3 = (zs[i3] + zs[i3 + 1] + zs[i3 + 2]) * (1.f / 3.f);
        float m  = fmaxf(S1, fmaxf(S2, S3));
        float a1 = __expf(S1 - m), a2 = __expf(S2 - m), a3 = __expf(S3 - m);
        o += (a1 * C1 + a2 * C2 + a3 * C3) / (a1 + a2 + a3);
    }
    out[(size_t)be * LOUT + d] = 0.5f * o;
}

// ---------------------------------------------------------------------------
extern "C" void kernel_launch(void* const* d_in, const int* in_sizes, int n_in,
                              void* d_out, int out_size, void* d_ws, size_t ws_size,
                              hipStream_t stream) {
    const float* x       = (const float*)d_in[0];
    const float* conv_w  = (const float*)d_in[1];
    const float* conv_b  = (const float*)d_in[2];
    const float* score_w = (const float*)d_in[3];
    float* out = (float*)d_out;
    float* ws  = (float*)d_ws;

    // workspace layout (floats): Wt[512*5*512] | y[B*E*LC] | z[B*LC]  (~140 MB)
    float* Wt = ws;
    float* y  = Wt + (size_t)E_ * K_ * E_;
    float* z  = y + (size_t)B_ * E_ * LC;

    wt_kernel<<<dim3((E_ * E_ * K_ + 255) / 256), 256, 0, stream>>>(conv_w, Wt);
    conv_kernel<<<dim3((LC + TT - 1) / TT, E_ / EE, B_), 256, 0, stream>>>(x, Wt, conv_b, y);
    zscore_kernel<<<dim3((LC + 255) / 256, B_), 256, 0, stream>>>(y, score_w, z);
    out_kernel<<<dim3(B_ * E_, LOUT / DTILE), 256, 0, stream>>>(y, z, out);
}

// Round 2
// 506.987 us; speedup vs baseline: 4.7744x; 4.7744x over previous
//
#include <hip/hip_runtime.h>
#include <math.h>

// Problem constants
#define B_    8
#define E_    512
#define L_    8192
#define K_    5
#define LC    8188      // L - K + 1
#define LOUT  4096      // L / DS

typedef float  f32x4  __attribute__((ext_vector_type(4)));
typedef short  s16x8  __attribute__((ext_vector_type(8)));

// float -> bf16 (RTNE, no NaN special-casing: inputs are well-behaved)
__device__ __forceinline__ unsigned short f2bf(float f) {
    union { float f; unsigned u; } v; v.f = f;
    unsigned r = v.u + 0x7FFFu + ((v.u >> 16) & 1u);
    return (unsigned short)(r >> 16);
}
__device__ __forceinline__ float bf2f(unsigned short h) {
    union { unsigned u; float f; } v; v.u = ((unsigned)h) << 16;
    return v.f;
}

// ---------------------------------------------------------------------------
// Kernel 0: pack conv weight [e][i][k] fp32 -> Wtb[k][e][i] bf16
// ---------------------------------------------------------------------------
__global__ __launch_bounds__(256) void wt_kernel(const float* __restrict__ w,
                                                 unsigned short* __restrict__ Wtb) {
    int idx = blockIdx.x * 256 + threadIdx.x;
    if (idx >= E_ * E_ * K_) return;
    int i    = idx & (E_ - 1);
    int rest = idx >> 9;            // k*E + e
    int e    = rest & (E_ - 1);
    int k    = rest >> 9;
    Wtb[idx] = f2bf(w[((size_t)e * E_ + i) * K_ + k]);
}

// ---------------------------------------------------------------------------
// Kernel 1: transpose x[b][i][t] fp32 -> xT[b][t][i] bf16 (64x64 LDS tiles)
// ---------------------------------------------------------------------------
__global__ __launch_bounds__(256) void xt_kernel(const float* __restrict__ x,
                                                 unsigned short* __restrict__ xT) {
    __shared__ float s[64][65];
    const int b  = blockIdx.z;
    const int i0 = blockIdx.y * 64;
    const int t0 = blockIdx.x * 64;
    #pragma unroll
    for (int j = 0; j < 16; ++j) {
        int idx = threadIdx.x + j * 256;
        int r = idx >> 6, c = idx & 63;       // r: i-offset, c: t-offset
        s[c][r] = x[((size_t)b * E_ + i0 + r) * L_ + t0 + c];
    }
    __syncthreads();
    #pragma unroll
    for (int j = 0; j < 16; ++j) {
        int idx = threadIdx.x + j * 256;
        int tt = idx >> 6, ii = idx & 63;
        xT[((size_t)b * L_ + t0 + tt) * E_ + i0 + ii] = f2bf(s[tt][ii]);
    }
}

// ---------------------------------------------------------------------------
// Kernel 2: implicit-GEMM conv via bf16 MFMA.
// y[b,e,t] = bias[e] + sum_{k,i} W[e,i,k] * x[b,i,t+k]
// Block: 64e x 256t, 4 waves, wave = 4x4 subtiles of 16x16x32.
// ---------------------------------------------------------------------------
__global__ __launch_bounds__(256) void conv_mfma(const unsigned short* __restrict__ xT,
                                                 const unsigned short* __restrict__ Wtb,
                                                 const float* __restrict__ bias,
                                                 unsigned short* __restrict__ y) {
    __shared__ unsigned short Ws[K_][64][40];   // rows padded to 80B: 2-way max
    __shared__ unsigned short Xs[260][40];

    const int tid  = threadIdx.x;
    const int nt   = blockIdx.x;
    const int b    = nt >> 5;
    const int t0   = (nt & 31) * 256;
    const int e0   = blockIdx.y * 64;
    const int wave = tid >> 6;
    const int lane = tid & 63;
    const int l16  = lane & 15;
    const int quad = lane >> 4;
    const int wt0  = wave * 64;

    f32x4 acc[4][4];
    #pragma unroll
    for (int a = 0; a < 4; ++a)
        #pragma unroll
        for (int c = 0; c < 4; ++c) acc[a][c] = (f32x4)0.f;

    const unsigned short* xbase = xT + ((size_t)b * L_ + t0) * E_;

    for (int i0 = 0; i0 < E_; i0 += 32) {
        // stage X: rows t0..t0+259, 32 i's each (16B chunks)  [1040 chunks]
        #pragma unroll
        for (int j = 0; j < 5; ++j) {
            int idx = tid + j * 256;
            if (idx < 1040) {
                int r = idx >> 2, c = idx & 3;
                s16x8 v = (s16x8)0;
                if (t0 + r < L_)
                    v = *(const s16x8*)(xbase + (size_t)r * E_ + i0 + c * 8);
                *(s16x8*)&Xs[r][c * 8] = v;
            }
        }
        // stage W: 5 tap-planes x 64 e x 32 i  [1280 chunks, exactly 5/thread]
        #pragma unroll
        for (int j = 0; j < 5; ++j) {
            int idx = tid + j * 256;
            int rl = idx >> 2, c = idx & 3;
            int k = rl >> 6, ep = rl & 63;
            *(s16x8*)&Ws[k][ep][c * 8] =
                *(const s16x8*)(Wtb + ((size_t)(k * E_ + e0 + ep) * E_ + i0 + c * 8));
        }
        __syncthreads();

        #pragma unroll
        for (int k = 0; k < K_; ++k) {
            s16x8 af[4], bfv[4];
            #pragma unroll
            for (int es = 0; es < 4; ++es)
                af[es] = *(const s16x8*)&Ws[k][es * 16 + l16][quad * 8];
            #pragma unroll
            for (int ts = 0; ts < 4; ++ts)
                bfv[ts] = *(const s16x8*)&Xs[wt0 + ts * 16 + l16 + k][quad * 8];
            #pragma unroll
            for (int es = 0; es < 4; ++es)
                #pragma unroll
                for (int ts = 0; ts < 4; ++ts)
                    acc[es][ts] = __builtin_amdgcn_mfma_f32_16x16x32_bf16(
                        af[es], bfv[ts], acc[es][ts], 0, 0, 0);
        }
        __syncthreads();
    }

    // epilogue: bias + store y (bf16). C layout: col(t)=lane&15, row(e)=quad*4+reg
    #pragma unroll
    for (int es = 0; es < 4; ++es) {
        #pragma unroll
        for (int ts = 0; ts < 4; ++ts) {
            int t = t0 + wt0 + ts * 16 + l16;
            if (t < LC) {
                #pragma unroll
                for (int reg = 0; reg < 4; ++reg) {
                    int e = e0 + es * 16 + quad * 4 + reg;
                    y[((size_t)b * E_ + e) * LC + t] = f2bf(acc[es][ts][reg] + bias[e]);
                }
            }
        }
    }
}

// ---------------------------------------------------------------------------
// Kernel 3: z[b,t] = sum_e y[b,e,t] * score_w[e]   (y is bf16, 2 t per thread)
// ---------------------------------------------------------------------------
__global__ __launch_bounds__(256) void zscore_kernel(const unsigned short* __restrict__ y,
                                                     const float* __restrict__ sw,
                                                     float* __restrict__ z) {
    __shared__ float s[E_];
    const int b = blockIdx.y;
    const int tp = (blockIdx.x * 256 + threadIdx.x) * 2;
    for (int i = threadIdx.x; i < E_; i += 256) s[i] = sw[i];
    __syncthreads();
    if (tp >= LC) return;
    const unsigned short* yb = y + (size_t)b * E_ * LC + tp;
    float a0 = 0, a1 = 0, b0 = 0, b1 = 0;
    #pragma unroll 4
    for (int e = 0; e < E_; e += 2) {
        unsigned v0 = *(const unsigned*)(yb + (size_t)(e + 0) * LC);
        unsigned v1 = *(const unsigned*)(yb + (size_t)(e + 1) * LC);
        a0 += bf2f((unsigned short)(v0 & 0xFFFF)) * s[e + 0];
        b0 += bf2f((unsigned short)(v0 >> 16))    * s[e + 0];
        a1 += bf2f((unsigned short)(v1 & 0xFFFF)) * s[e + 1];
        b1 += bf2f((unsigned short)(v1 >> 16))    * s[e + 1];
    }
    z[(size_t)b * LC + tp]     = a0 + a1;
    z[(size_t)b * LC + tp + 1] = b0 + b1;
}

// ---------------------------------------------------------------------------
// Kernel 4: blend widths 1..3 with softmax(z-scores), then 2x downsample.
// ---------------------------------------------------------------------------
#define DTILE 256
#define STAGE 520
__global__ __launch_bounds__(256) void out_kernel(const unsigned short* __restrict__ y,
                                                  const float* __restrict__ z,
                                                  float* __restrict__ out) {
    __shared__ float ys[STAGE];
    __shared__ float zs[STAGE];
    const int be = blockIdx.x;          // b*E + e
    const int b  = be >> 9;
    const int d0 = blockIdx.y * DTILE;
    const int tb = d0 * 2;
    const unsigned short* yrow = y + (size_t)be * LC;
    const float* zrow = z + (size_t)b * LC;
    for (int i = threadIdx.x; i < STAGE; i += 256) {
        int t = tb - 2 + i;
        bool v = (t >= 0) && (t < LC);
        ys[i] = v ? bf2f(yrow[t]) : 0.f;
        zs[i] = v ? zrow[t] : 0.f;
    }
    __syncthreads();
    const int d = d0 + threadIdx.x;
    float o = 0.f;
    #pragma unroll
    for (int half = 0; half < 2; ++half) {
        int t = 2 * d + half;
        int j = t - tb + 2;
        float C1 = ys[j], S1 = zs[j];
        int i2 = (t & ~1) - tb + 2;
        float C2 = 0.5f * (ys[i2] + ys[i2 + 1]);
        float S2 = 0.5f * (zs[i2] + zs[i2 + 1]);
        int i3 = (t / 3) * 3 - tb + 2;
        float C3 = (ys[i3] + ys[i3 + 1] + ys[i3 + 2]) * (1.f / 3.f);
        float S3 = (zs[i3] + zs[i3 + 1] + zs[i3 + 2]) * (1.f / 3.f);
        float m  = fmaxf(S1, fmaxf(S2, S3));
        float a1 = __expf(S1 - m), a2 = __expf(S2 - m), a3 = __expf(S3 - m);
        o += (a1 * C1 + a2 * C2 + a3 * C3) / (a1 + a2 + a3);
    }
    out[(size_t)be * LOUT + d] = 0.5f * o;
}

// ---------------------------------------------------------------------------
extern "C" void kernel_launch(void* const* d_in, const int* in_sizes, int n_in,
                              void* d_out, int out_size, void* d_ws, size_t ws_size,
                              hipStream_t stream) {
    const float* x       = (const float*)d_in[0];
    const float* conv_w  = (const float*)d_in[1];
    const float* conv_b  = (const float*)d_in[2];
    const float* score_w = (const float*)d_in[3];
    float* out = (float*)d_out;

    // workspace (ushort units): Wtb[5*512*512] | xT[B*L*E] | y[B*E*LC] | z fp32[B*LC]
    unsigned short* base = (unsigned short*)d_ws;
    unsigned short* Wtb = base;
    unsigned short* xT  = Wtb + (size_t)K_ * E_ * E_;        // 1,310,720
    unsigned short* y   = xT + (size_t)B_ * L_ * E_;         // +33,554,432
    float*          z   = (float*)(y + (size_t)B_ * E_ * LC); // +33,538,048 (even)

    wt_kernel<<<dim3((E_ * E_ * K_ + 255) / 256), 256, 0, stream>>>(conv_w, Wtb);
    xt_kernel<<<dim3(L_ / 64, E_ / 64, B_), 256, 0, stream>>>(x, xT);
    conv_mfma<<<dim3(B_ * 32, E_ / 64), 256, 0, stream>>>(xT, Wtb, conv_b, y);
    zscore_kernel<<<dim3(16, B_), 256, 0, stream>>>(y, score_w, z);
    out_kernel<<<dim3(B_ * E_, LOUT / DTILE), 256, 0, stream>>>(y, z, out);
}

// Round 3
// 448.571 us; speedup vs baseline: 5.3961x; 1.1302x over previous
//
#include <hip/hip_runtime.h>
#include <math.h>

// Problem constants
#define B_    8
#define E_    512
#define L_    8192
#define K_    5
#define LC    8188      // L - K + 1
#define LOUT  4096      // L / DS
#define LPAD  8256      // xT padded t-length (129 * 64), rows >= L_ are zero

typedef float  f32x4   __attribute__((ext_vector_type(4)));
typedef float  f32x16  __attribute__((ext_vector_type(16)));
typedef short  s16x4   __attribute__((ext_vector_type(4)));
typedef short  s16x8   __attribute__((ext_vector_type(8)));

__device__ __forceinline__ unsigned short f2bf(float f) {
    union { float f; unsigned u; } v; v.f = f;
    unsigned r = v.u + 0x7FFFu + ((v.u >> 16) & 1u);
    return (unsigned short)(r >> 16);
}
__device__ __forceinline__ float bf2f(unsigned short h) {
    union { unsigned u; float f; } v; v.u = ((unsigned)h) << 16;
    return v.f;
}

// ---------------------------------------------------------------------------
// Kernel 0: pack conv weight [e][i][k] fp32 -> Wtb[k][e][i] bf16
// ---------------------------------------------------------------------------
__global__ __launch_bounds__(256) void wt_kernel(const float* __restrict__ w,
                                                 unsigned short* __restrict__ Wtb) {
    int idx = blockIdx.x * 256 + threadIdx.x;
    if (idx >= E_ * E_ * K_) return;
    int i    = idx & (E_ - 1);
    int rest = idx >> 9;            // k*E + e
    int e    = rest & (E_ - 1);
    int k    = rest >> 9;
    Wtb[idx] = f2bf(w[((size_t)e * E_ + i) * K_ + k]);
}

// ---------------------------------------------------------------------------
// Kernel 1: transpose x[b][i][t] fp32 -> xT[b][t][i] bf16, t padded to LPAD
// with zeros. 8-byte vector stores.
// ---------------------------------------------------------------------------
__global__ __launch_bounds__(256) void xt_kernel(const float* __restrict__ x,
                                                 unsigned short* __restrict__ xT) {
    __shared__ float s[64][65];
    const int b  = blockIdx.z;
    const int i0 = blockIdx.y * 64;
    const int t0 = blockIdx.x * 64;
    #pragma unroll
    for (int j = 0; j < 16; ++j) {
        int idx = threadIdx.x + j * 256;
        int r = idx >> 6, c = idx & 63;       // r: i-offset, c: t-offset
        int t = t0 + c;
        s[c][r] = (t < L_) ? x[((size_t)b * E_ + i0 + r) * L_ + t] : 0.f;
    }
    __syncthreads();
    #pragma unroll
    for (int j = 0; j < 4; ++j) {
        int idx = threadIdx.x + j * 256;
        int tt = idx >> 4, ig = (idx & 15) * 4;
        s16x4 v;
        v[0] = (short)f2bf(s[tt][ig + 0]);
        v[1] = (short)f2bf(s[tt][ig + 1]);
        v[2] = (short)f2bf(s[tt][ig + 2]);
        v[3] = (short)f2bf(s[tt][ig + 3]);
        *(s16x4*)&xT[((size_t)b * LPAD + t0 + tt) * E_ + i0 + ig] = v;
    }
}

// ---------------------------------------------------------------------------
// Kernel 2: zero z[B][LC] (fp32)
// ---------------------------------------------------------------------------
__global__ __launch_bounds__(256) void zero_z(float* __restrict__ z) {
    int idx = blockIdx.x * 256 + threadIdx.x;
    if (idx < (B_ * LC) / 4) ((f32x4*)z)[idx] = (f32x4)0.f;
}

// ---------------------------------------------------------------------------
// Kernel 3: implicit-GEMM conv via 32x32x16 bf16 MFMA + fused z-score.
// Block: 64e x 512t, 4 waves, wave = 64e x 128t (2x4 subtiles of 32x32).
// Software-pipelined staging (prefetch next K-tile into VGPRs during MFMA).
// ---------------------------------------------------------------------------
__global__ __launch_bounds__(256, 2) void conv_mfma(const unsigned short* __restrict__ xT,
                                                    const unsigned short* __restrict__ Wtb,
                                                    const float* __restrict__ bias,
                                                    const float* __restrict__ sw,
                                                    unsigned short* __restrict__ y,
                                                    float* __restrict__ z) {
    __shared__ unsigned short Xs[520][40];   // rows padded to 80 B (conflict-free)
    __shared__ unsigned short Ws[K_][64][40];
    __shared__ float swb[128];               // [0:64) = score_w, [64:128) = bias

    const int tid  = threadIdx.x;
    const int nt   = blockIdx.x;
    const int b    = nt >> 4;
    const int tb   = (nt & 15) * 512;
    const int e0   = blockIdx.y * 64;
    const int wave = tid >> 6;
    const int lane = tid & 63;
    const int l32  = lane & 31;
    const int hi   = lane >> 5;
    const int wt0  = wave * 128;

    if (tid < 64)       swb[tid] = sw[e0 + tid];
    else if (tid < 128) swb[tid] = bias[e0 + tid - 64];

    f32x16 acc[2][4];
    #pragma unroll
    for (int es = 0; es < 2; ++es)
        #pragma unroll
        for (int ts = 0; ts < 4; ++ts) acc[es][ts] = (f32x16)0.f;

    const unsigned short* xbase = xT + ((size_t)b * LPAD + tb) * E_;

    // prefetch registers: X 2080 chunks (8 full + 32-thread tail), W 1280 chunks
    s16x8 xpf[9];
    s16x8 wpf[5];

    auto load_tile = [&](int i0) {
        #pragma unroll
        for (int j = 0; j < 8; ++j) {
            int idx = tid + j * 256;
            int r = idx >> 2, c = idx & 3;
            xpf[j] = *(const s16x8*)(xbase + (size_t)r * E_ + i0 + c * 8);
        }
        {
            int idx = tid + 2048;
            if (idx < 2080) {
                int r = idx >> 2, c = idx & 3;
                xpf[8] = *(const s16x8*)(xbase + (size_t)r * E_ + i0 + c * 8);
            }
        }
        #pragma unroll
        for (int j = 0; j < 5; ++j) {
            int idx = tid + j * 256;
            int rl = idx >> 2, c = idx & 3;
            int k = rl >> 6, ep = rl & 63;
            wpf[j] = *(const s16x8*)(Wtb + ((size_t)(k * E_ + e0 + ep) * E_ + i0 + c * 8));
        }
    };
    auto store_tile = [&]() {
        #pragma unroll
        for (int j = 0; j < 8; ++j) {
            int idx = tid + j * 256;
            int r = idx >> 2, c = idx & 3;
            *(s16x8*)&Xs[r][c * 8] = xpf[j];
        }
        {
            int idx = tid + 2048;
            if (idx < 2080) {
                int r = idx >> 2, c = idx & 3;
                *(s16x8*)&Xs[r][c * 8] = xpf[8];
            }
        }
        #pragma unroll
        for (int j = 0; j < 5; ++j) {
            int idx = tid + j * 256;
            int rl = idx >> 2, c = idx & 3;
            int k = rl >> 6, ep = rl & 63;
            *(s16x8*)&Ws[k][ep][c * 8] = wpf[j];
        }
    };

    load_tile(0);
    for (int i0 = 0; i0 < E_; i0 += 32) {
        __syncthreads();            // previous compute done reading LDS
        store_tile();
        __syncthreads();
        if (i0 + 32 < E_) load_tile(i0 + 32);   // latency hidden under MFMAs

        #pragma unroll
        for (int k = 0; k < K_; ++k) {
            #pragma unroll
            for (int kk = 0; kk < 2; ++kk) {
                const int co = kk * 16 + hi * 8;
                s16x8 a0 = *(const s16x8*)&Ws[k][l32][co];
                s16x8 a1 = *(const s16x8*)&Ws[k][32 + l32][co];
                #pragma unroll
                for (int ts = 0; ts < 4; ++ts) {
                    s16x8 bv = *(const s16x8*)&Xs[wt0 + ts * 32 + l32 + k][co];
                    acc[0][ts] = __builtin_amdgcn_mfma_f32_32x32x16_bf16(a0, bv, acc[0][ts], 0, 0, 0);
                    acc[1][ts] = __builtin_amdgcn_mfma_f32_32x32x16_bf16(a1, bv, acc[1][ts], 0, 0, 0);
                }
            }
        }
    }

    // Epilogue: bias add, y store (bf16), fused z partial via shuffle + atomic.
    // C/D layout (32x32): col(t)=lane&31, row(e)=(reg&3)+8*(reg>>2)+4*hi
    #pragma unroll
    for (int ts = 0; ts < 4; ++ts) {
        const int t = tb + wt0 + ts * 32 + l32;
        const bool tv = (t < LC);
        float zp = 0.f;
        #pragma unroll
        for (int es = 0; es < 2; ++es) {
            #pragma unroll
            for (int reg = 0; reg < 16; ++reg) {
                int er = es * 32 + (reg & 3) + 8 * (reg >> 2) + 4 * hi;
                float v = acc[es][ts][reg] + swb[64 + er];
                if (tv) y[((size_t)b * E_ + e0 + er) * LC + t] = f2bf(v);
                zp += swb[er] * v;
            }
        }
        zp += __shfl_xor(zp, 32);
        if (hi == 0 && tv) atomicAdd(&z[(size_t)b * LC + t], zp);
    }
}

// ---------------------------------------------------------------------------
// Kernel 4: blend widths 1..3 with softmax(z-scores), then 2x downsample.
// ---------------------------------------------------------------------------
#define DTILE 256
#define STAGE 520
__global__ __launch_bounds__(256) void out_kernel(const unsigned short* __restrict__ y,
                                                  const float* __restrict__ z,
                                                  float* __restrict__ out) {
    __shared__ float ys[STAGE];
    __shared__ float zs[STAGE];
    const int be = blockIdx.x;          // b*E + e
    const int b  = be >> 9;
    const int d0 = blockIdx.y * DTILE;
    const int tb = d0 * 2;
    const unsigned short* yrow = y + (size_t)be * LC;
    const float* zrow = z + (size_t)b * LC;
    for (int i = threadIdx.x; i < STAGE; i += 256) {
        int t = tb - 2 + i;
        bool v = (t >= 0) && (t < LC);
        ys[i] = v ? bf2f(yrow[t]) : 0.f;
        zs[i] = v ? zrow[t] : 0.f;
    }
    __syncthreads();
    const int d = d0 + threadIdx.x;
    float o = 0.f;
    #pragma unroll
    for (int half = 0; half < 2; ++half) {
        int t = 2 * d + half;
        int j = t - tb + 2;
        float C1 = ys[j], S1 = zs[j];
        int i2 = (t & ~1) - tb + 2;
        float C2 = 0.5f * (ys[i2] + ys[i2 + 1]);
        float S2 = 0.5f * (zs[i2] + zs[i2 + 1]);
        int i3 = (t / 3) * 3 - tb + 2;
        float C3 = (ys[i3] + ys[i3 + 1] + ys[i3 + 2]) * (1.f / 3.f);
        float S3 = (zs[i3] + zs[i3 + 1] + zs[i3 + 2]) * (1.f / 3.f);
        float m  = fmaxf(S1, fmaxf(S2, S3));
        float a1 = __expf(S1 - m), a2 = __expf(S2 - m), a3 = __expf(S3 - m);
        o += (a1 * C1 + a2 * C2 + a3 * C3) / (a1 + a2 + a3);
    }
    out[(size_t)be * LOUT + d] = 0.5f * o;
}

// ---------------------------------------------------------------------------
extern "C" void kernel_launch(void* const* d_in, const int* in_sizes, int n_in,
                              void* d_out, int out_size, void* d_ws, size_t ws_size,
                              hipStream_t stream) {
    const float* x       = (const float*)d_in[0];
    const float* conv_w  = (const float*)d_in[1];
    const float* conv_b  = (const float*)d_in[2];
    const float* score_w = (const float*)d_in[3];
    float* out = (float*)d_out;

    // workspace (ushort units): Wtb[5*512*512] | xT[B*LPAD*E] | y[B*E*LC] | z fp32[B*LC]
    unsigned short* base = (unsigned short*)d_ws;
    unsigned short* Wtb = base;
    unsigned short* xT  = Wtb + (size_t)K_ * E_ * E_;          // 1,310,720
    unsigned short* y   = xT + (size_t)B_ * LPAD * E_;         // +33,816,576
    float*          z   = (float*)(y + (size_t)B_ * E_ * LC);  // +33,538,048

    wt_kernel<<<dim3((E_ * E_ * K_ + 255) / 256), 256, 0, stream>>>(conv_w, Wtb);
    xt_kernel<<<dim3(LPAD / 64, E_ / 64, B_), 256, 0, stream>>>(x, xT);
    zero_z<<<dim3((B_ * LC / 4 + 255) / 256), 256, 0, stream>>>(z);
    conv_mfma<<<dim3(B_ * 16, E_ / 64), 256, 0, stream>>>(xT, Wtb, conv_b, score_w, y, z);
    out_kernel<<<dim3(B_ * E_, LOUT / DTILE), 256, 0, stream>>>(y, z, out);
}